// Round 1
// baseline (1358.638 us; speedup 1.0000x reference)
//
#include <hip/hip_runtime.h>
#include <cstdint>
#include <cstddef>

// Problem constants
#define BDIM  16
#define SDIM  4096
#define HIDD  768
#define HEADS 12
#define DHEAD 64
#define KD    768                 // K dim of all big GEMMs (= HID = QKV)
#define MROWS (BDIM*SDIM)         // 65536
#define BH    (BDIM*HEADS)        // 192

typedef __bf16 bf16x8 __attribute__((ext_vector_type(8)));
typedef float  floatx4 __attribute__((ext_vector_type(4)));

__device__ __forceinline__ floatx4 mfma16(bf16x8 a, bf16x8 b, floatx4 c) {
    return __builtin_amdgcn_mfma_f32_16x16x32_bf16(a, b, c, 0, 0, 0);
}

// ---------------------------------------------------------------------------
// Transpose 768x768 fp32 -> bf16 [n][k]
// ---------------------------------------------------------------------------
__global__ __launch_bounds__(256) void transpose_w(const float* __restrict__ in,
                                                   __bf16* __restrict__ outp)
{
    __shared__ float tile[64][65];
    const int t = threadIdx.x;
    const int k0 = blockIdx.y * 64, n0 = blockIdx.x * 64;
    const int r = t >> 6, c = t & 63;
#pragma unroll
    for (int i = 0; i < 16; ++i) {
        const int rr = i * 4 + r;
        tile[rr][c] = in[(size_t)(k0 + rr) * KD + n0 + c];
    }
    __syncthreads();
#pragma unroll
    for (int i = 0; i < 16; ++i) {
        const int rr = i * 4 + r;
        outp[(size_t)(n0 + rr) * KD + k0 + c] = (__bf16)tile[c][rr];
    }
}

// ---------------------------------------------------------------------------
// Main GEMM: C[M=65536, N=768] = A[M,768] @ B^T[768(n),768(k)]  (bf16 MFMA)
// MODE 0: Q  : y=(acc+b)*mask -> elu+1 -> *0.125 -> bf16, normal [row][col]
// MODE 1: K  : same as Q but store head-transposed [bh][d][s]
// MODE 2: V  : y=(acc+b)*mask -> bf16, head-transposed [bh][d][s]
// MODE 3: OUT: y= acc+b -> fp32, normal layout
// AF32: A operand is fp32 (converted to bf16 during staging)
// ---------------------------------------------------------------------------
template<int MODE, bool AF32>
__global__ __launch_bounds__(256) void gemm_kernel(const void* __restrict__ Aptr,
                                                   const __bf16* __restrict__ Bt,
                                                   const float* __restrict__ bias,
                                                   const float* __restrict__ mask,
                                                   void* __restrict__ Cptr)
{
    __shared__ __align__(16) __bf16 As[128][72];
    __shared__ __align__(16) __bf16 Bs[128][72];
    const int t  = threadIdx.x;
    const int n0 = blockIdx.x * 128;
    const int m0 = blockIdx.y * 128;
    const int w = t >> 6, l = t & 63, l15 = l & 15, q = l >> 4;
    const int wm = (w >> 1) * 64, wn = (w & 1) * 64;

    const floatx4 fzero = {0.f, 0.f, 0.f, 0.f};
    floatx4 acc[4][4];
#pragma unroll
    for (int mt = 0; mt < 4; ++mt)
#pragma unroll
        for (int nt = 0; nt < 4; ++nt) acc[mt][nt] = fzero;

    for (int kt = 0; kt < KD; kt += 64) {
#pragma unroll
        for (int i = 0; i < 4; ++i) {
            const int idx = t + i * 256;        // 0..1023
            const int row = idx >> 3, part = idx & 7;
            if (AF32) {
                const float* ap = (const float*)Aptr + (size_t)(m0 + row) * KD + kt + part * 8;
                const float4 f0 = *(const float4*)ap;
                const float4 f1 = *(const float4*)(ap + 4);
                bf16x8 val;
                val[0] = (__bf16)f0.x; val[1] = (__bf16)f0.y;
                val[2] = (__bf16)f0.z; val[3] = (__bf16)f0.w;
                val[4] = (__bf16)f1.x; val[5] = (__bf16)f1.y;
                val[6] = (__bf16)f1.z; val[7] = (__bf16)f1.w;
                *(bf16x8*)&As[row][part * 8] = val;
            } else {
                *(bf16x8*)&As[row][part * 8] =
                    *(const bf16x8*)((const __bf16*)Aptr + (size_t)(m0 + row) * KD + kt + part * 8);
            }
            *(bf16x8*)&Bs[row][part * 8] =
                *(const bf16x8*)(Bt + (size_t)(n0 + row) * KD + kt + part * 8);
        }
        __syncthreads();
#pragma unroll
        for (int ks = 0; ks < 2; ++ks) {
            bf16x8 af[4], bfv[4];
#pragma unroll
            for (int mt = 0; mt < 4; ++mt)
                af[mt] = *(const bf16x8*)&As[wm + mt * 16 + l15][ks * 32 + q * 8];
#pragma unroll
            for (int nt = 0; nt < 4; ++nt)
                bfv[nt] = *(const bf16x8*)&Bs[wn + nt * 16 + l15][ks * 32 + q * 8];
#pragma unroll
            for (int mt = 0; mt < 4; ++mt)
#pragma unroll
                for (int nt = 0; nt < 4; ++nt)
                    acc[mt][nt] = mfma16(af[mt], bfv[nt], acc[mt][nt]);
        }
        __syncthreads();
    }

    // Epilogue. C/D layout: col = lane&15, row = (lane>>4)*4 + reg.
#pragma unroll
    for (int mt = 0; mt < 4; ++mt) {
#pragma unroll
        for (int r = 0; r < 4; ++r) {
            const int grow = m0 + wm + mt * 16 + q * 4 + r;
            float mk = 1.0f;
            if (MODE <= 2) mk = mask[grow];
#pragma unroll
            for (int nt = 0; nt < 4; ++nt) {
                const int gcol = n0 + wn + nt * 16 + l15;
                float v = acc[mt][nt][r] + bias[gcol];
                if (MODE <= 2) v *= mk;
                if (MODE <= 1) {                       // elu(q)+1, then *1/sqrt(D)
                    v = (v > 0.f) ? (v + 1.f) : __expf(v);
                    v *= 0.125f;
                }
                if (MODE == 3) {
                    ((float*)Cptr)[(size_t)grow * KD + gcol] = v;
                } else if (MODE == 0) {
                    ((__bf16*)Cptr)[(size_t)grow * KD + gcol] = (__bf16)v;
                } else {
                    // head-transposed: [(b*H + h)*64 + d][s]
                    const size_t addr =
                        (((size_t)(grow >> 12) * HEADS + (gcol >> 6)) * DHEAD + (gcol & 63)) * (size_t)SDIM
                        + (grow & (SDIM - 1));
                    ((__bf16*)Cptr)[addr] = (__bf16)v;
                }
            }
        }
    }
}

// ---------------------------------------------------------------------------
// kv accumulation: kvf[bh][n][d] (+= over s), n<64: kv[d][n]; n==64: ksum[d]
// K,V given head-transposed [bh*64 + d][4096(s)] so reduction dim s is contiguous.
// ---------------------------------------------------------------------------
__global__ __launch_bounds__(256) void kv_kernel(const __bf16* __restrict__ Kt,
                                                 const __bf16* __restrict__ Vt,
                                                 float* __restrict__ kvf)
{
    __shared__ __align__(16) __bf16 Kl[64][72];
    __shared__ __align__(16) __bf16 Vl[64][72];
    const int t = threadIdx.x;
    const int bh = blockIdx.y;
    const int s_begin = blockIdx.x * 256;
    const int w = t >> 6, l = t & 63, l15 = l & 15, q = l >> 4;
    const size_t headbase = (size_t)bh * DHEAD * SDIM;

    const floatx4 fzero = {0.f, 0.f, 0.f, 0.f};
    floatx4 acc[5];
#pragma unroll
    for (int i = 0; i < 5; ++i) acc[i] = fzero;

    bf16x8 onesfrag;
    {
        const __bf16 one = (l15 == 0) ? (__bf16)1.0f : (__bf16)0.0f;
#pragma unroll
        for (int j = 0; j < 8; ++j) onesfrag[j] = one;
    }

    for (int c = 0; c < 4; ++c) {
        const int s0 = s_begin + c * 64;
        __syncthreads();
#pragma unroll
        for (int i = 0; i < 2; ++i) {
            const int idx = t + i * 256;       // 0..511
            const int dr = idx >> 3, part = idx & 7;
            const size_t g = headbase + (size_t)dr * SDIM + s0 + part * 8;
            *(bf16x8*)&Kl[dr][part * 8] = *(const bf16x8*)(Kt + g);
            *(bf16x8*)&Vl[dr][part * 8] = *(const bf16x8*)(Vt + g);
        }
        __syncthreads();
#pragma unroll
        for (int ks = 0; ks < 2; ++ks) {
            const bf16x8 af = *(const bf16x8*)&Kl[w * 16 + l15][ks * 32 + q * 8];
#pragma unroll
            for (int nt = 0; nt < 4; ++nt) {
                const bf16x8 bfv = *(const bf16x8*)&Vl[nt * 16 + l15][ks * 32 + q * 8];
                acc[nt] = mfma16(af, bfv, acc[nt]);
            }
            acc[4] = mfma16(af, onesfrag, acc[4]);
        }
    }

    float* base = kvf + (size_t)bh * 65 * 64;
#pragma unroll
    for (int nt = 0; nt < 4; ++nt) {
        const int n = nt * 16 + l15;
#pragma unroll
        for (int r = 0; r < 4; ++r) {
            const int d = w * 16 + q * 4 + r;
            atomicAdd(base + n * 64 + d, acc[nt][r]);
        }
    }
    if (l15 == 0) {
#pragma unroll
        for (int r = 0; r < 4; ++r) {
            const int d = w * 16 + q * 4 + r;
            atomicAdd(base + 64 * 64 + d, acc[4][r]);
        }
    }
}

__global__ __launch_bounds__(256) void conv_kvb(const float* __restrict__ in,
                                                __bf16* __restrict__ outp)
{
    const int i = blockIdx.x * 256 + threadIdx.x;
    if (i < BH * 65 * 64) outp[i] = (__bf16)in[i];
}

// ---------------------------------------------------------------------------
// attn[s][hd] = (q @ kv) / (q . ksum), per (b,h); output merged-head layout
// ---------------------------------------------------------------------------
__global__ __launch_bounds__(256) void attn_kernel(const __bf16* __restrict__ Qb,
                                                   const __bf16* __restrict__ kvb,
                                                   __bf16* __restrict__ attn)
{
    __shared__ __align__(16) __bf16 Bl[80][72];
    const int t = threadIdx.x;
    const int bh = blockIdx.y;
    const int b = bh / HEADS, h = bh % HEADS;
    const int s0 = blockIdx.x * 64;
    const int w = t >> 6, l = t & 63, l15 = l & 15, q = l >> 4;

    const __bf16* src = kvb + (size_t)bh * 65 * 64;
    for (int idx = t; idx < 80 * 64; idx += 256) {
        const int n = idx >> 6;
        Bl[n][idx & 63] = (n < 65) ? src[idx] : (__bf16)0.0f;
    }
    __syncthreads();

    const size_t qrow = ((size_t)b * SDIM + s0 + w * 16 + l15) * KD + h * DHEAD;
    const floatx4 fzero = {0.f, 0.f, 0.f, 0.f};
    floatx4 acc[5];
#pragma unroll
    for (int i = 0; i < 5; ++i) acc[i] = fzero;

#pragma unroll
    for (int ks = 0; ks < 2; ++ks) {
        const bf16x8 af = *(const bf16x8*)(Qb + qrow + ks * 32 + q * 8);
#pragma unroll
        for (int nt = 0; nt < 5; ++nt) {
            const bf16x8 bfv = *(const bf16x8*)&Bl[nt * 16 + l15][ks * 32 + q * 8];
            acc[nt] = mfma16(af, bfv, acc[nt]);
        }
    }

    const size_t outbase = ((size_t)b * SDIM + s0 + w * 16) * KD + h * DHEAD;
#pragma unroll
    for (int r = 0; r < 4; ++r) {
        const float den = __shfl(acc[4][r], (l & 48), 64);  // lane with l15==0 holds col 64
        const float inv = 1.0f / den;
#pragma unroll
        for (int nt = 0; nt < 4; ++nt) {
            attn[outbase + (size_t)(q * 4 + r) * KD + nt * 16 + l15] =
                (__bf16)(acc[nt][r] * inv);
        }
    }
}

// ---------------------------------------------------------------------------
extern "C" void kernel_launch(void* const* d_in, const int* in_sizes, int n_in,
                              void* d_out, int out_size, void* d_ws, size_t ws_size,
                              hipStream_t stream)
{
    const float* x    = (const float*)d_in[0];
    const float* mask = (const float*)d_in[1];
    const float* Wq   = (const float*)d_in[2];
    const float* bq   = (const float*)d_in[3];
    const float* Wk   = (const float*)d_in[4];
    const float* bk   = (const float*)d_in[5];
    const float* Wv   = (const float*)d_in[6];
    const float* bv   = (const float*)d_in[7];
    const float* Wo   = (const float*)d_in[8];
    const float* bo   = (const float*)d_in[9];
    float* out = (float*)d_out;

    char* ws = (char*)d_ws;
    size_t off = 0;
    auto alloc = [&](size_t bytes) -> void* {
        void* p = ws + off;
        off += (bytes + 255) & ~(size_t)255;
        return p;
    };
    __bf16* Qb  = (__bf16*)alloc((size_t)MROWS * KD * 2);
    __bf16* Ktb = (__bf16*)alloc((size_t)MROWS * KD * 2);   // K head-transposed; reused as attn
    __bf16* Vtb = (__bf16*)alloc((size_t)MROWS * KD * 2);   // V head-transposed
    __bf16* Wqt = (__bf16*)alloc((size_t)KD * KD * 2);
    __bf16* Wkt = (__bf16*)alloc((size_t)KD * KD * 2);
    __bf16* Wvt = (__bf16*)alloc((size_t)KD * KD * 2);
    __bf16* Wot = (__bf16*)alloc((size_t)KD * KD * 2);
    float*  kvf = (float*)alloc((size_t)BH * 65 * 64 * 4);
    __bf16* kvb = (__bf16*)alloc((size_t)BH * 65 * 64 * 2);
    __bf16* attn = Ktb;  // K dead after kv_kernel

    hipMemsetAsync(kvf, 0, (size_t)BH * 65 * 64 * 4, stream);

    dim3 tgrid(12, 12);
    transpose_w<<<tgrid, 256, 0, stream>>>(Wq, Wqt);
    transpose_w<<<tgrid, 256, 0, stream>>>(Wk, Wkt);
    transpose_w<<<tgrid, 256, 0, stream>>>(Wv, Wvt);
    transpose_w<<<tgrid, 256, 0, stream>>>(Wo, Wot);

    dim3 ggrid(KD / 128, MROWS / 128);  // (6, 512)
    gemm_kernel<0, true><<<ggrid, 256, 0, stream>>>(x, Wqt, bq, mask, Qb);
    gemm_kernel<1, true><<<ggrid, 256, 0, stream>>>(x, Wkt, bk, mask, Ktb);
    gemm_kernel<2, true><<<ggrid, 256, 0, stream>>>(x, Wvt, bv, mask, Vtb);

    kv_kernel<<<dim3(16, BH), 256, 0, stream>>>(Ktb, Vtb, kvf);
    conv_kvb<<<(BH * 65 * 64) / 256, 256, 0, stream>>>(kvf, kvb);
    attn_kernel<<<dim3(SDIM / 64, BH), 256, 0, stream>>>(Qb, kvb, attn);

    gemm_kernel<3, false><<<ggrid, 256, 0, stream>>>(attn, Wot, bo, nullptr, out);
}

// Round 2
// 981.847 us; speedup vs baseline: 1.3838x; 1.3838x over previous
//
#include <hip/hip_runtime.h>
#include <cstdint>
#include <cstddef>

// Problem constants
#define BDIM  16
#define SDIM  4096
#define HEADS 12
#define DHEAD 64
#define KD    768                 // K dim of all big GEMMs (= HID = QKV)
#define MROWS (BDIM*SDIM)         // 65536
#define BH    (BDIM*HEADS)        // 192
#define NTOT  2304                // 3*768 fused QKV output columns

typedef __bf16 bf16x8 __attribute__((ext_vector_type(8)));
typedef __bf16 bf16x4 __attribute__((ext_vector_type(4)));
typedef float  floatx4 __attribute__((ext_vector_type(4)));

__device__ __forceinline__ floatx4 mfma16(bf16x8 a, bf16x8 b, floatx4 c) {
    return __builtin_amdgcn_mfma_f32_16x16x32_bf16(a, b, c, 0, 0, 0);
}

// async global->LDS, 16B per lane; LDS dest = wave-uniform base + lane*16
__device__ __forceinline__ void load_lds16(const __bf16* g, __bf16* l) {
    __builtin_amdgcn_global_load_lds((const __attribute__((address_space(1))) void*)g,
                                     (__attribute__((address_space(3))) void*)l,
                                     16, 0, 0);
}

// ---------------------------------------------------------------------------
// Transpose 768x768 fp32 -> bf16 [n][k]
// ---------------------------------------------------------------------------
__global__ __launch_bounds__(256) void transpose_w(const float* __restrict__ in,
                                                   __bf16* __restrict__ outp)
{
    __shared__ float tile[64][65];
    const int t = threadIdx.x;
    const int k0 = blockIdx.y * 64, n0 = blockIdx.x * 64;
    const int r = t >> 6, c = t & 63;
#pragma unroll
    for (int i = 0; i < 16; ++i) {
        const int rr = i * 4 + r;
        tile[rr][c] = in[(size_t)(k0 + rr) * KD + n0 + c];
    }
    __syncthreads();
#pragma unroll
    for (int i = 0; i < 16; ++i) {
        const int rr = i * 4 + r;
        outp[(size_t)(n0 + rr) * KD + k0 + c] = (__bf16)tile[c][rr];
    }
}

__global__ __launch_bounds__(256) void pack_bias(const float* __restrict__ bq,
                                                 const float* __restrict__ bk,
                                                 const float* __restrict__ bv,
                                                 float* __restrict__ dst)
{
    const int i = blockIdx.x * 256 + threadIdx.x;
    if (i < NTOT)
        dst[i] = (i < 768) ? bq[i] : (i < 1536) ? bk[i - 768] : bv[i - 1536];
}

// ---------------------------------------------------------------------------
// Fused QKV GEMM: C[M=65536, N=2304] = x[M,768] @ Wt^T  (bf16 MFMA)
// A: fp32 x, converted to bf16 during register staging (padded LDS).
// B: bf16 Wt [2304][768] staged via global_load_lds with XOR swizzle.
// Epilogue: +bias, *mask, elu+1 & *0.125 for Q/K; bf16 store, normal layout.
// XCD swizzle: each XCD owns a contiguous band of 64 m-strips.
// ---------------------------------------------------------------------------
__global__ __launch_bounds__(256, 3) void gemm_qkv(const float* __restrict__ X,
                                                   const __bf16* __restrict__ Bt,
                                                   const float* __restrict__ biasAll,
                                                   const float* __restrict__ mask,
                                                   __bf16* __restrict__ Qb,
                                                   __bf16* __restrict__ Kb,
                                                   __bf16* __restrict__ Vb)
{
    __shared__ __align__(16) __bf16 As[128 * 72];   // padded, reg-staged
    __shared__ __align__(16) __bf16 Bs[128 * 64];   // unpadded, swizzled, lds-direct

    const int id  = blockIdx.x;                // 0..9215
    const int xcd = id & 7;
    const int jj  = id >> 3;                   // 0..1151
    const int by  = xcd * 64 + jj / 18;        // m-strip, banded per XCD
    const int bx  = jj - (jj / 18) * 18;       // 0..17
    const int m0  = by * 128;
    const int n0g = bx * 128;                  // global col in [0,2304)
    const int matrix = bx / 6;                 // 0=Q,1=K,2=V
    const int c0 = (bx - matrix * 6) * 128;    // col within the matrix

    const int t = threadIdx.x;
    const int w = t >> 6, l = t & 63, l15 = l & 15, q = l >> 4;
    const int wm = (w >> 1) * 64, wn = (w & 1) * 64;

    const floatx4 fzero = {0.f, 0.f, 0.f, 0.f};
    floatx4 acc[4][4];
#pragma unroll
    for (int mt = 0; mt < 4; ++mt)
#pragma unroll
        for (int nt = 0; nt < 4; ++nt) acc[mt][nt] = fzero;

    for (int kt = 0; kt < KD; kt += 64) {
        // B tile via lds-direct (16 pages of 1KB; wave w does pages w*4..w*4+3)
#pragma unroll
        for (int i = 0; i < 4; ++i) {
            const int page = w * 4 + i;
            const int row  = page * 8 + (l >> 3);
            const int plog = (l & 7) ^ (row & 7);
            load_lds16(Bt + (size_t)(n0g + row) * KD + kt + plog * 8, &Bs[page * 512]);
        }
        // A tile: fp32 -> bf16 register staging into padded LDS
#pragma unroll
        for (int i = 0; i < 4; ++i) {
            const int idx = t + i * 256;       // 0..1023
            const int row = idx >> 3, part = idx & 7;
            const float* ap = X + (size_t)(m0 + row) * KD + kt + part * 8;
            const float4 f0 = *(const float4*)ap;
            const float4 f1 = *(const float4*)(ap + 4);
            bf16x8 val;
            val[0] = (__bf16)f0.x; val[1] = (__bf16)f0.y;
            val[2] = (__bf16)f0.z; val[3] = (__bf16)f0.w;
            val[4] = (__bf16)f1.x; val[5] = (__bf16)f1.y;
            val[6] = (__bf16)f1.z; val[7] = (__bf16)f1.w;
            *(bf16x8*)&As[row * 72 + part * 8] = val;
        }
        __syncthreads();
#pragma unroll
        for (int ks = 0; ks < 2; ++ks) {
            bf16x8 af[4], bfv[4];
#pragma unroll
            for (int mt = 0; mt < 4; ++mt)
                af[mt] = *(const bf16x8*)&As[(wm + mt * 16 + l15) * 72 + ks * 32 + q * 8];
#pragma unroll
            for (int nt = 0; nt < 4; ++nt) {
                const int rb = wn + nt * 16 + l15;
                bfv[nt] = *(const bf16x8*)&Bs[rb * 64 + (((ks * 4 + q) ^ (l15 & 7)) * 8)];
            }
#pragma unroll
            for (int mt = 0; mt < 4; ++mt)
#pragma unroll
                for (int nt = 0; nt < 4; ++nt)
                    acc[mt][nt] = mfma16(af[mt], bfv[nt], acc[mt][nt]);
        }
        __syncthreads();
    }

    __bf16* Cb = (matrix == 0) ? Qb : (matrix == 1) ? Kb : Vb;
    // C/D layout: col = lane&15, row = (lane>>4)*4 + reg.
#pragma unroll
    for (int mt = 0; mt < 4; ++mt) {
#pragma unroll
        for (int r = 0; r < 4; ++r) {
            const int grow = m0 + wm + mt * 16 + q * 4 + r;
            const float mk = mask[grow];
#pragma unroll
            for (int nt = 0; nt < 4; ++nt) {
                const int ncol = wn + nt * 16 + l15;
                float v = acc[mt][nt][r] + biasAll[n0g + ncol];
                v *= mk;
                if (matrix < 2) {              // elu+1, then 1/sqrt(D)
                    v = (v > 0.f) ? (v + 1.f) : __expf(v);
                    v *= 0.125f;
                }
                Cb[(size_t)grow * KD + c0 + ncol] = (__bf16)v;
            }
        }
    }
}

// ---------------------------------------------------------------------------
// OUT GEMM: out[M,768] = attn[M,768] @ Wot^T + bo  (fp32 store)
// Both operands staged via global_load_lds, XOR-swizzled unpadded LDS.
// ---------------------------------------------------------------------------
__global__ __launch_bounds__(256, 3) void gemm_out(const __bf16* __restrict__ Ab,
                                                   const __bf16* __restrict__ Bt,
                                                   const float* __restrict__ bias,
                                                   float* __restrict__ out)
{
    __shared__ __align__(16) __bf16 As[128 * 64];
    __shared__ __align__(16) __bf16 Bs[128 * 64];

    const int id  = blockIdx.x;                // 0..3071
    const int xcd = id & 7;
    const int jj  = id >> 3;                   // 0..383
    const int by  = xcd * 64 + jj / 6;
    const int bx  = jj - (jj / 6) * 6;
    const int m0  = by * 128;
    const int n0  = bx * 128;

    const int t = threadIdx.x;
    const int w = t >> 6, l = t & 63, l15 = l & 15, q = l >> 4;
    const int wm = (w >> 1) * 64, wn = (w & 1) * 64;

    const floatx4 fzero = {0.f, 0.f, 0.f, 0.f};
    floatx4 acc[4][4];
#pragma unroll
    for (int mt = 0; mt < 4; ++mt)
#pragma unroll
        for (int nt = 0; nt < 4; ++nt) acc[mt][nt] = fzero;

    for (int kt = 0; kt < KD; kt += 64) {
#pragma unroll
        for (int i = 0; i < 4; ++i) {
            const int page = w * 4 + i;
            const int row  = page * 8 + (l >> 3);
            const int plog = (l & 7) ^ (row & 7);
            load_lds16(Ab + (size_t)(m0 + row) * KD + kt + plog * 8, &As[page * 512]);
            load_lds16(Bt + (size_t)(n0 + row) * KD + kt + plog * 8, &Bs[page * 512]);
        }
        __syncthreads();
#pragma unroll
        for (int ks = 0; ks < 2; ++ks) {
            bf16x8 af[4], bfv[4];
#pragma unroll
            for (int mt = 0; mt < 4; ++mt) {
                const int ra = wm + mt * 16 + l15;
                af[mt] = *(const bf16x8*)&As[ra * 64 + (((ks * 4 + q) ^ (l15 & 7)) * 8)];
            }
#pragma unroll
            for (int nt = 0; nt < 4; ++nt) {
                const int rb = wn + nt * 16 + l15;
                bfv[nt] = *(const bf16x8*)&Bs[rb * 64 + (((ks * 4 + q) ^ (l15 & 7)) * 8)];
            }
#pragma unroll
            for (int mt = 0; mt < 4; ++mt)
#pragma unroll
                for (int nt = 0; nt < 4; ++nt)
                    acc[mt][nt] = mfma16(af[mt], bfv[nt], acc[mt][nt]);
        }
        __syncthreads();
    }

#pragma unroll
    for (int mt = 0; mt < 4; ++mt) {
#pragma unroll
        for (int r = 0; r < 4; ++r) {
            const int grow = m0 + wm + mt * 16 + q * 4 + r;
#pragma unroll
            for (int nt = 0; nt < 4; ++nt) {
                const int gcol = n0 + wn + nt * 16 + l15;
                out[(size_t)grow * KD + gcol] = acc[mt][nt][r] + bias[gcol];
            }
        }
    }
}

// ---------------------------------------------------------------------------
// kv accumulation from NORMAL-layout K,V [65536][768]:
// kvf[bh][e][d] += sum_s K[s][d]*V[s][e];  e==64 row: ksum[d].
// Transpose happens on the LDS fragment-read side (scalar u16 reads).
// ---------------------------------------------------------------------------
__global__ __launch_bounds__(256) void kv_kernel(const __bf16* __restrict__ Kb,
                                                 const __bf16* __restrict__ Vb,
                                                 float* __restrict__ kvf)
{
    __shared__ __align__(16) __bf16 Kl[64][68];
    __shared__ __align__(16) __bf16 Vl[64][68];
    const int t = threadIdx.x;
    const int bh = blockIdx.y;
    const int b = bh / HEADS, h = bh % HEADS;
    const int sp = blockIdx.x;                 // 0..3 (s split)
    const int w = t >> 6, l = t & 63, l15 = l & 15, q = l >> 4;

    const size_t rowbase = ((size_t)b * SDIM + sp * 1024) * KD + h * DHEAD;

    const floatx4 fzero = {0.f, 0.f, 0.f, 0.f};
    floatx4 acc[5];
#pragma unroll
    for (int i = 0; i < 5; ++i) acc[i] = fzero;

    bf16x8 onesfrag;
    {
        const __bf16 one = (l15 == 0) ? (__bf16)1.0f : (__bf16)0.0f;
#pragma unroll
        for (int j = 0; j < 8; ++j) onesfrag[j] = one;
    }

    for (int tile = 0; tile < 16; ++tile) {
        __syncthreads();
#pragma unroll
        for (int i = 0; i < 2; ++i) {
            const int idx = t + i * 256;       // 0..511
            const int row = idx >> 3, part = idx & 7;
            const size_t g = rowbase + (size_t)(tile * 64 + row) * KD + part * 8;
            const bf16x8 kvv = *(const bf16x8*)(Kb + g);
            const bf16x8 vvv = *(const bf16x8*)(Vb + g);
            *(bf16x4*)&Kl[row][part * 8]     = *(const bf16x4*)&kvv;
            *(bf16x4*)&Kl[row][part * 8 + 4] = *((const bf16x4*)&kvv + 1);
            *(bf16x4*)&Vl[row][part * 8]     = *(const bf16x4*)&vvv;
            *(bf16x4*)&Vl[row][part * 8 + 4] = *((const bf16x4*)&vvv + 1);
        }
        __syncthreads();
#pragma unroll
        for (int ks = 0; ks < 2; ++ks) {
            bf16x8 af;
#pragma unroll
            for (int j = 0; j < 8; ++j)
                af[j] = Kl[ks * 32 + q * 8 + j][w * 16 + l15];   // K^T frag (m=d)
#pragma unroll
            for (int nt = 0; nt < 4; ++nt) {
                bf16x8 bfv;
#pragma unroll
                for (int j = 0; j < 8; ++j)
                    bfv[j] = Vl[ks * 32 + q * 8 + j][nt * 16 + l15];  // V frag (n=e)
                acc[nt] = mfma16(af, bfv, acc[nt]);
            }
            acc[4] = mfma16(af, onesfrag, acc[4]);
        }
    }

    float* base = kvf + (size_t)bh * 65 * 64;
#pragma unroll
    for (int nt = 0; nt < 4; ++nt) {
        const int e = nt * 16 + l15;
#pragma unroll
        for (int r = 0; r < 4; ++r) {
            const int d = w * 16 + q * 4 + r;
            atomicAdd(base + e * 64 + d, acc[nt][r]);
        }
    }
    if (l15 == 0) {
#pragma unroll
        for (int r = 0; r < 4; ++r) {
            const int d = w * 16 + q * 4 + r;
            atomicAdd(base + 64 * 64 + d, acc[4][r]);
        }
    }
}

__global__ __launch_bounds__(256) void conv_kvb(const float* __restrict__ in,
                                                __bf16* __restrict__ outp)
{
    const int i = blockIdx.x * 256 + threadIdx.x;
    if (i < BH * 65 * 64) outp[i] = (__bf16)in[i];
}

// ---------------------------------------------------------------------------
// attn[s][hd] = (q @ kv) / (q . ksum), per (b,h); output merged-head layout
// ---------------------------------------------------------------------------
__global__ __launch_bounds__(256) void attn_kernel(const __bf16* __restrict__ Qb,
                                                   const __bf16* __restrict__ kvb,
                                                   __bf16* __restrict__ attn)
{
    __shared__ __align__(16) __bf16 Bl[80][72];
    const int t = threadIdx.x;
    const int bh = blockIdx.y;
    const int b = bh / HEADS, h = bh % HEADS;
    const int s0 = blockIdx.x * 64;
    const int w = t >> 6, l = t & 63, l15 = l & 15, q = l >> 4;

    const __bf16* src = kvb + (size_t)bh * 65 * 64;
    for (int idx = t; idx < 80 * 64; idx += 256) {
        const int n = idx >> 6;
        Bl[n][idx & 63] = (n < 65) ? src[idx] : (__bf16)0.0f;
    }
    __syncthreads();

    const size_t qrow = ((size_t)b * SDIM + s0 + w * 16 + l15) * KD + h * DHEAD;
    const floatx4 fzero = {0.f, 0.f, 0.f, 0.f};
    floatx4 acc[5];
#pragma unroll
    for (int i = 0; i < 5; ++i) acc[i] = fzero;

#pragma unroll
    for (int ks = 0; ks < 2; ++ks) {
        const bf16x8 af = *(const bf16x8*)(Qb + qrow + ks * 32 + q * 8);
#pragma unroll
        for (int nt = 0; nt < 5; ++nt) {
            const bf16x8 bfv = *(const bf16x8*)&Bl[nt * 16 + l15][ks * 32 + q * 8];
            acc[nt] = mfma16(af, bfv, acc[nt]);
        }
    }

    const size_t outbase = ((size_t)b * SDIM + s0 + w * 16) * KD + h * DHEAD;
#pragma unroll
    for (int r = 0; r < 4; ++r) {
        const float den = __shfl(acc[4][r], (l & 48), 64);  // lane with l15==0 holds col 64
        const float inv = 1.0f / den;
#pragma unroll
        for (int nt = 0; nt < 4; ++nt) {
            attn[outbase + (size_t)(q * 4 + r) * KD + nt * 16 + l15] =
                (__bf16)(acc[nt][r] * inv);
        }
    }
}

// ---------------------------------------------------------------------------
extern "C" void kernel_launch(void* const* d_in, const int* in_sizes, int n_in,
                              void* d_out, int out_size, void* d_ws, size_t ws_size,
                              hipStream_t stream)
{
    const float* x    = (const float*)d_in[0];
    const float* mask = (const float*)d_in[1];
    const float* Wq   = (const float*)d_in[2];
    const float* bq   = (const float*)d_in[3];
    const float* Wk   = (const float*)d_in[4];
    const float* bk   = (const float*)d_in[5];
    const float* Wv   = (const float*)d_in[6];
    const float* bv   = (const float*)d_in[7];
    const float* Wo   = (const float*)d_in[8];
    const float* bo   = (const float*)d_in[9];
    float* out = (float*)d_out;

    char* ws = (char*)d_ws;
    size_t off = 0;
    auto alloc = [&](size_t bytes) -> void* {
        void* p = ws + off;
        off += (bytes + 255) & ~(size_t)255;
        return p;
    };
    __bf16* Qb   = (__bf16*)alloc((size_t)MROWS * KD * 2);
    __bf16* Kb   = (__bf16*)alloc((size_t)MROWS * KD * 2);   // reused as attn
    __bf16* Vb   = (__bf16*)alloc((size_t)MROWS * KD * 2);
    __bf16* Wt   = (__bf16*)alloc((size_t)NTOT * KD * 2);    // [Wq^T;Wk^T;Wv^T]
    __bf16* Wot  = (__bf16*)alloc((size_t)KD * KD * 2);
    float*  bAll = (float*)alloc((size_t)NTOT * 4);
    float*  kvf  = (float*)alloc((size_t)BH * 65 * 64 * 4);
    __bf16* kvb  = (__bf16*)alloc((size_t)BH * 65 * 64 * 2);
    __bf16* attn = Kb;  // K dead after kv_kernel

    hipMemsetAsync(kvf, 0, (size_t)BH * 65 * 64 * 4, stream);

    dim3 tgrid(12, 12);
    transpose_w<<<tgrid, 256, 0, stream>>>(Wq, Wt);
    transpose_w<<<tgrid, 256, 0, stream>>>(Wk, Wt + (size_t)KD * KD);
    transpose_w<<<tgrid, 256, 0, stream>>>(Wv, Wt + (size_t)2 * KD * KD);
    transpose_w<<<tgrid, 256, 0, stream>>>(Wo, Wot);
    pack_bias<<<9, 256, 0, stream>>>(bq, bk, bv, bAll);

    gemm_qkv<<<(NTOT / 128) * (MROWS / 128), 256, 0, stream>>>(x, Wt, bAll, mask, Qb, Kb, Vb);

    kv_kernel<<<dim3(4, BH), 256, 0, stream>>>(Kb, Vb, kvf);
    conv_kvb<<<(BH * 65 * 64) / 256, 256, 0, stream>>>(kvf, kvb);
    attn_kernel<<<dim3(SDIM / 64, BH), 256, 0, stream>>>(Qb, kvb, attn);

    gemm_out<<<(KD / 128) * (MROWS / 128), 256, 0, stream>>>(attn, Wot, bo, out);
}